// Round 4
// baseline (421.798 us; speedup 1.0000x reference)
//
#include <hip/hip_runtime.h>
#include <hip/hip_fp16.h>

// ---------------- fused-scan constants ----------------
// Session findings (r0-r15):
//  - ~185us is the empirical divergent-gather floor for this op: 25.6M random
//    lanes (Wh + x) at ~4.3 cyc/lane/CU of TA address throughput. Four
//    structurally different kernels (fused 5-pass, 1-pass binned x3) all
//    converge here with HBM<=15%, VALU<=18%, no saturated counter.
//  - Split (bin + dense-scan) designs pay the same gather floor in prep PLUS
//    scan overhead -> strictly worse than fused (413 vs 314).
//  - Remaining recoverable cost is auxiliary: reduce kernel + partials traffic
//    + workspace footprint. This version merges LDS acc directly into y with
//    rotated dense atomics (ws: 41MB -> 2MB, reduce5 eliminated).
#define PARTS 5
#define NPP 40960                  // 5*40960 = 204800 >= 200000
#define NXCD 8
#define GRP 6
#define NCHUNKS (NXCD * GRP)       // 48 chunks; grid = 240 blocks (~1/CU)
#define TPB_SCAN 1024

typedef int   vint4   __attribute__((ext_vector_type(4)));
typedef float vfloat4 __attribute__((ext_vector_type(4)));

// ---------------- Phase 0: W f32 -> f16 (2MB table => L2-resident gathers) ----
__global__ __launch_bounds__(256) void wconv_kernel(
    const float* __restrict__ W, __half* __restrict__ Wh, int n)
{
    int i4 = (blockIdx.x * 256 + threadIdx.x) * 4;
    if (i4 + 3 < n) {
        vfloat4 w = *reinterpret_cast<const vfloat4*>(W + i4);
        __half2 h01 = __floats2half2_rn(w.x, w.y);
        __half2 h23 = __floats2half2_rn(w.z, w.w);
        *reinterpret_cast<__half2*>(Wh + i4)     = h01;
        *reinterpret_cast<__half2*>(Wh + i4 + 2) = h23;
    } else {
        for (; i4 < n; ++i4) Wh[i4] = __float2half(W[i4]);
    }
}

// ---------------- Phase 1: y = bias[label] (also the atomic-merge base) ------
__global__ __launch_bounds__(256) void bias_init_kernel(
    const float* __restrict__ Param_b, const int* __restrict__ node_label,
    float* __restrict__ y, int n_nodes)
{
    int i = blockIdx.x * blockDim.x + threadIdx.x;
    if (i < n_nodes) y[i] = Param_b[node_label[i]];
}

// ---------------- Phase 2: fused pipelined gather/scan, direct-y merge -------
// Proven r13 structure (XCD-aware chunk mapping, fp16 W, rotated 2-stage
// pipeline). New: epilogue merges the per-(partition,chunk) LDS accumulator
// straight into y with unsafeAtomicAdd instead of writing partials.
//  - merge start rotated per-chunk so the 48 same-partition writers hit
//    different cache lines when they finish (they finish nearly together).
//  - zero entries skipped (~27% of slots at E/N=64, 48 chunks).
__global__ __launch_bounds__(TPB_SCAN) void fscan_kernel(
    const float* __restrict__ x, const __half* __restrict__ Wh,
    const int* __restrict__ src, const int* __restrict__ widx,
    const int* __restrict__ dst,
    float* __restrict__ y, int E, int chunk, int n_nodes)
{
    extern __shared__ float acc[];   // NPP floats = 160 KB
    int xcd = blockIdx.x % NXCD;
    int q   = blockIdx.x / NXCD;     // [0, 30)
    int p   = q % PARTS;
    int g   = q / PARTS;             // [0, GRP)
    int c   = g * NXCD + xcd;        // chunk id in [0, 48)

    float4* z4 = reinterpret_cast<float4*>(acc);
    for (int i = threadIdx.x; i < NPP / 4; i += TPB_SCAN)
        z4[i] = make_float4(0.f, 0.f, 0.f, 0.f);
    __syncthreads();

    int lo = c * chunk;              // chunk is a multiple of 4
    int hi = min(E, lo + chunk);     // E is a multiple of 4
    int base = p * NPP;

    const vint4* d4 = reinterpret_cast<const vint4*>(dst);
    const vint4* s4 = reinterpret_cast<const vint4*>(src);
    const vint4* w4 = reinterpret_cast<const vint4*>(widx);

    int ghi = hi / 4;
    int gi  = lo / 4 + threadIdx.x;

    // ---- stage A (prologue) ----
    unsigned rA0 = NPP, rA1 = NPP, rA2 = NPP, rA3 = NPP;
    float aA0 = 0.f, aA1 = 0.f, aA2 = 0.f, aA3 = 0.f;
    float bA0 = 0.f, bA1 = 0.f, bA2 = 0.f, bA3 = 0.f;
    bool haveA = (gi < ghi);
    if (haveA) {
        vint4 d = d4[gi], s = s4[gi], w = w4[gi];
        rA0 = (unsigned)(d.x - base); rA1 = (unsigned)(d.y - base);
        rA2 = (unsigned)(d.z - base); rA3 = (unsigned)(d.w - base);
        if (rA0 < NPP) { aA0 = __half2float(Wh[w.x]); bA0 = x[s.x]; }
        if (rA1 < NPP) { aA1 = __half2float(Wh[w.y]); bA1 = x[s.y]; }
        if (rA2 < NPP) { aA2 = __half2float(Wh[w.z]); bA2 = x[s.z]; }
        if (rA3 < NPP) { aA3 = __half2float(Wh[w.w]); bA3 = x[s.w]; }
    }

    while (haveA) {
        // ---- issue stage B (loads in flight across A's atomics) ----
        int gj = gi + TPB_SCAN;
        bool haveB = (gj < ghi);
        unsigned rB0 = NPP, rB1 = NPP, rB2 = NPP, rB3 = NPP;
        float aB0 = 0.f, aB1 = 0.f, aB2 = 0.f, aB3 = 0.f;
        float bB0 = 0.f, bB1 = 0.f, bB2 = 0.f, bB3 = 0.f;
        if (haveB) {
            vint4 d = d4[gj], s = s4[gj], w = w4[gj];
            rB0 = (unsigned)(d.x - base); rB1 = (unsigned)(d.y - base);
            rB2 = (unsigned)(d.z - base); rB3 = (unsigned)(d.w - base);
            if (rB0 < NPP) { aB0 = __half2float(Wh[w.x]); bB0 = x[s.x]; }
            if (rB1 < NPP) { aB1 = __half2float(Wh[w.y]); bB1 = x[s.y]; }
            if (rB2 < NPP) { aB2 = __half2float(Wh[w.z]); bB2 = x[s.z]; }
            if (rB3 < NPP) { aB3 = __half2float(Wh[w.w]); bB3 = x[s.w]; }
        }

        // ---- consume stage A (register-resident; no memory wait) ----
        if (rA0 < NPP) unsafeAtomicAdd(&acc[rA0], aA0 * bA0);
        if (rA1 < NPP) unsafeAtomicAdd(&acc[rA1], aA1 * bA1);
        if (rA2 < NPP) unsafeAtomicAdd(&acc[rA2], aA2 * bA2);
        if (rA3 < NPP) unsafeAtomicAdd(&acc[rA3], aA3 * bA3);

        // ---- rotate B -> A (vmcnt wait lands here, after the atomics) ----
        rA0 = rB0; rA1 = rB1; rA2 = rB2; rA3 = rB3;
        aA0 = aB0; aA1 = aB1; aA2 = aB2; aA3 = aB3;
        bA0 = bB0; bA1 = bB1; bA2 = bB2; bA3 = bB3;
        gi = gj; haveA = haveB;
    }
    __syncthreads();

    // ---- epilogue: rotated direct atomic merge into y ----
    const int NQ = NPP / 4;                       // 10240 float4 groups
    int rot = (c * 1237) & (NQ - 1);              // per-chunk rotation (NQ pow2)
    const vfloat4* av4 = reinterpret_cast<const vfloat4*>(acc);
    for (int t = threadIdx.x; t < NQ; t += TPB_SCAN) {
        int i = t + rot; if (i >= NQ) i -= NQ;
        int node = base + i * 4;
        vfloat4 v = av4[i];
        if (node + 3 < n_nodes) {
            if (v.x != 0.f) unsafeAtomicAdd(&y[node + 0], v.x);
            if (v.y != 0.f) unsafeAtomicAdd(&y[node + 1], v.y);
            if (v.z != 0.f) unsafeAtomicAdd(&y[node + 2], v.z);
            if (v.w != 0.f) unsafeAtomicAdd(&y[node + 3], v.w);
        } else if (node < n_nodes) {
            for (int j = 0; j < 4; ++j)
                if (node + j < n_nodes && v[j] != 0.f)
                    unsafeAtomicAdd(&y[node + j], v[j]);
        }
    }
}

// ---------------- Fallback (direct atomics) if ws too small ----------------
__global__ __launch_bounds__(256) void edge_scatter_kernel(
    const float* __restrict__ x, const float* __restrict__ Param_W,
    const int* __restrict__ src, const int* __restrict__ dst,
    const int* __restrict__ widx, float* __restrict__ y, int n_edges)
{
    int i = (blockIdx.x * blockDim.x + threadIdx.x) * 4;
    if (i + 3 < n_edges) {
        int4 s = *reinterpret_cast<const int4*>(src + i);
        int4 d = *reinterpret_cast<const int4*>(dst + i);
        int4 w = *reinterpret_cast<const int4*>(widx + i);
        unsafeAtomicAdd(&y[d.x], Param_W[w.x] * x[s.x]);
        unsafeAtomicAdd(&y[d.y], Param_W[w.y] * x[s.y]);
        unsafeAtomicAdd(&y[d.z], Param_W[w.z] * x[s.z]);
        unsafeAtomicAdd(&y[d.w], Param_W[w.w] * x[s.w]);
    } else {
        for (; i < n_edges; ++i)
            unsafeAtomicAdd(&y[dst[i]], Param_W[widx[i]] * x[src[i]]);
    }
}

extern "C" void kernel_launch(void* const* d_in, const int* in_sizes, int n_in,
                              void* d_out, int out_size, void* d_ws, size_t ws_size,
                              hipStream_t stream)
{
    const float* x          = (const float*)d_in[0];
    const float* Param_W    = (const float*)d_in[1];
    const float* Param_b    = (const float*)d_in[2];
    const int*   src        = (const int*)d_in[3];
    const int*   dst        = (const int*)d_in[4];
    const int*   weight_idx = (const int*)d_in[5];
    const int*   node_label = (const int*)d_in[6];
    float* y = (float*)d_out;

    int n_nodes = in_sizes[0];
    int W_n     = in_sizes[1];
    int E       = in_sizes[3];

    size_t wh_bytes = ((size_t)W_n * sizeof(__half) + 255) & ~(size_t)255;  // 2MB

    if (ws_size >= wh_bytes) {
        __half* Wh = (__half*)d_ws;

        // Phase 0: convert W to fp16 (ws re-poisoned every launch -> always rerun)
        int t0 = (W_n + 3) / 4;
        wconv_kernel<<<(t0 + 255) / 256, 256, 0, stream>>>(Param_W, Wh, W_n);

        // Phase 1: y = bias[label]  (atomic-merge base; same-stream ordering)
        bias_init_kernel<<<(n_nodes + 255) / 256, 256, 0, stream>>>(
            Param_b, node_label, y, n_nodes);

        // Phase 2: fused pipelined gather+scan, direct atomic merge into y
        int chunk = (((E + NCHUNKS - 1) / NCHUNKS) + 3) & ~3;  // mult of 4
        fscan_kernel<<<PARTS * NCHUNKS, TPB_SCAN, NPP * sizeof(float), stream>>>(
            x, Wh, src, weight_idx, dst, y, E, chunk, n_nodes);
    } else {
        bias_init_kernel<<<(n_nodes + 255) / 256, 256, 0, stream>>>(
            Param_b, node_label, y, n_nodes);
        int t = (E + 3) / 4;
        edge_scatter_kernel<<<(t + 255) / 256, 256, 0, stream>>>(
            x, Param_W, src, dst, weight_idx, y, E);
    }
}

// Round 6
// 314.969 us; speedup vs baseline: 1.3392x; 1.3392x over previous
//
#include <hip/hip_runtime.h>
#include <hip/hip_fp16.h>

// ---------------- Fused pipelined broadcast-5 constants ----------------
// ROOFLINE NOTE (this session, r0-r18): the binding resource is the per-CU
// random-gather line throughput: 25.6M divergent gather lanes (Wh[widx] +
// x[src], 2 per edge) at a measured ~4.3-4.6 cyc/line/CU, validated on two
// independent structures (fused fscan 193us; dense-gather prep 180us), and
// occupancy-insensitive (40% vs 78% -> same rate). Floor ~178us kernel +
// ~105us harness-invariant overhead + ~18us aux ~= 301-310us. Attempts that
// regressed: 1-pass bin+dense-scan (413-421: pays the same gather floor in
// prep PLUS ~120us scan/reduce), direct-y atomic merge (422: 7.2M global fp32
// atomics bounce lines across 8 non-coherent XCD L2s, WRITE_SIZE 38->137MB).
#define PARTS 5
#define NPP 40960                  // nodes per partition; 5*40960 = 204800 >= 200000
#define PADDED_N (PARTS * NPP)     // 204800
#define NXCD 8
#define GRP 6
#define NCHUNKS (NXCD * GRP)       // 48 chunks; grid = 240 blocks (1/CU, XCD-mapped)
#define TPB_SCAN 1024

typedef int   vint4   __attribute__((ext_vector_type(4)));
typedef float vfloat4 __attribute__((ext_vector_type(4)));

// ---------------- Phase 0: W f32 -> f16 (2MB table => L2-resident gathers) ----------------
__global__ __launch_bounds__(256) void wconv_kernel(
    const float* __restrict__ W, __half* __restrict__ Wh, int n)
{
    int i4 = (blockIdx.x * 256 + threadIdx.x) * 4;
    if (i4 + 3 < n) {
        vfloat4 w = *reinterpret_cast<const vfloat4*>(W + i4);
        __half2 h01 = __floats2half2_rn(w.x, w.y);
        __half2 h23 = __floats2half2_rn(w.z, w.w);
        *reinterpret_cast<__half2*>(Wh + i4)     = h01;
        *reinterpret_cast<__half2*>(Wh + i4 + 2) = h23;
    } else {
        for (; i4 < n; ++i4) Wh[i4] = __float2half(W[i4]);
    }
}

// ---------------- Fused + software-pipelined gather/scan ----------------
// Accumulated lessons: XCD-aware mapping (r9: chunk's 5 readers share
// blockIdx%8 -> same XCD L2); fp16 W (r10: gathers L2-hit); temporal stream
// loads (r7: NT killed LLC reuse); PARTS=5 minimum passes (r11: passes cost
// issue); rotated 2-stage pipeline (r13). r17: unsafeAtomicAdd on LDS acc
// (native ds_add_f32) -- LDS pipe overlaps under the gather floor; partials +
// reduce5 epilogue is the proven-cheapest merge (direct-y atomics regressed).
__global__ __launch_bounds__(TPB_SCAN) void fscan_kernel(
    const float* __restrict__ x, const __half* __restrict__ Wh,
    const int* __restrict__ src, const int* __restrict__ widx,
    const int* __restrict__ dst,
    float* __restrict__ partials, int E, int chunk)
{
    extern __shared__ float acc[];   // NPP floats = 160 KB
    int xcd = blockIdx.x % NXCD;
    int q   = blockIdx.x / NXCD;     // [0, 30)
    int p   = q % PARTS;
    int g   = q / PARTS;             // [0, GRP)
    int c   = g * NXCD + xcd;        // chunk id in [0, 48)

    float4* z4 = reinterpret_cast<float4*>(acc);
    for (int i = threadIdx.x; i < NPP / 4; i += TPB_SCAN)
        z4[i] = make_float4(0.f, 0.f, 0.f, 0.f);
    __syncthreads();

    int lo = c * chunk;              // chunk is a multiple of 4
    int hi = min(E, lo + chunk);     // E is a multiple of 4
    int base = p * NPP;

    const vint4* d4 = reinterpret_cast<const vint4*>(dst);
    const vint4* s4 = reinterpret_cast<const vint4*>(src);
    const vint4* w4 = reinterpret_cast<const vint4*>(widx);

    int ghi = hi / 4;
    int gi  = lo / 4 + threadIdx.x;

    // ---- stage A (prologue) ----
    unsigned rA0 = NPP, rA1 = NPP, rA2 = NPP, rA3 = NPP;
    float aA0 = 0.f, aA1 = 0.f, aA2 = 0.f, aA3 = 0.f;
    float bA0 = 0.f, bA1 = 0.f, bA2 = 0.f, bA3 = 0.f;
    bool haveA = (gi < ghi);
    if (haveA) {
        vint4 d = d4[gi], s = s4[gi], w = w4[gi];
        rA0 = (unsigned)(d.x - base); rA1 = (unsigned)(d.y - base);
        rA2 = (unsigned)(d.z - base); rA3 = (unsigned)(d.w - base);
        if (rA0 < NPP) { aA0 = __half2float(Wh[w.x]); bA0 = x[s.x]; }
        if (rA1 < NPP) { aA1 = __half2float(Wh[w.y]); bA1 = x[s.y]; }
        if (rA2 < NPP) { aA2 = __half2float(Wh[w.z]); bA2 = x[s.z]; }
        if (rA3 < NPP) { aA3 = __half2float(Wh[w.w]); bA3 = x[s.w]; }
    }

    while (haveA) {
        // ---- issue stage B (loads in flight across A's atomics) ----
        int gj = gi + TPB_SCAN;
        bool haveB = (gj < ghi);
        unsigned rB0 = NPP, rB1 = NPP, rB2 = NPP, rB3 = NPP;
        float aB0 = 0.f, aB1 = 0.f, aB2 = 0.f, aB3 = 0.f;
        float bB0 = 0.f, bB1 = 0.f, bB2 = 0.f, bB3 = 0.f;
        if (haveB) {
            vint4 d = d4[gj], s = s4[gj], w = w4[gj];
            rB0 = (unsigned)(d.x - base); rB1 = (unsigned)(d.y - base);
            rB2 = (unsigned)(d.z - base); rB3 = (unsigned)(d.w - base);
            if (rB0 < NPP) { aB0 = __half2float(Wh[w.x]); bB0 = x[s.x]; }
            if (rB1 < NPP) { aB1 = __half2float(Wh[w.y]); bB1 = x[s.y]; }
            if (rB2 < NPP) { aB2 = __half2float(Wh[w.z]); bB2 = x[s.z]; }
            if (rB3 < NPP) { aB3 = __half2float(Wh[w.w]); bB3 = x[s.w]; }
        }

        // ---- consume stage A (register-resident; no memory wait) ----
        if (rA0 < NPP) unsafeAtomicAdd(&acc[rA0], aA0 * bA0);
        if (rA1 < NPP) unsafeAtomicAdd(&acc[rA1], aA1 * bA1);
        if (rA2 < NPP) unsafeAtomicAdd(&acc[rA2], aA2 * bA2);
        if (rA3 < NPP) unsafeAtomicAdd(&acc[rA3], aA3 * bA3);

        // ---- rotate B -> A (vmcnt wait lands here, after the atomics) ----
        rA0 = rB0; rA1 = rB1; rA2 = rB2; rA3 = rB3;
        aA0 = aB0; aA1 = aB1; aA2 = aB2; aA3 = aB3;
        bA0 = bB0; bA1 = bB1; bA2 = bB2; bA3 = bB3;
        gi = gj; haveA = haveB;
    }
    __syncthreads();

    vfloat4* out4 = reinterpret_cast<vfloat4*>(partials + (size_t)c * PADDED_N + base);
    const vfloat4* av4 = reinterpret_cast<const vfloat4*>(acc);
    for (int i = threadIdx.x; i < NPP / 4; i += TPB_SCAN)
        __builtin_nontemporal_store(av4[i], out4 + i);
}

// ---------------- Reduce: 48 slices + bias ----------------
__global__ __launch_bounds__(256) void reduce5_kernel(
    const float* __restrict__ partials, const float* __restrict__ bias,
    const int* __restrict__ label, float* __restrict__ y, int n)
{
    int i = blockIdx.x * 256 + threadIdx.x;
    if (i >= n) return;
    float s0 = bias[label[i]];
    float s1 = 0.f, s2 = 0.f, s3 = 0.f;
    const float* p = partials + i;
    #pragma unroll 1
    for (int c = 0; c < NCHUNKS; c += 4) {
        s0 += __builtin_nontemporal_load(p + (size_t)(c + 0) * PADDED_N);
        s1 += __builtin_nontemporal_load(p + (size_t)(c + 1) * PADDED_N);
        s2 += __builtin_nontemporal_load(p + (size_t)(c + 2) * PADDED_N);
        s3 += __builtin_nontemporal_load(p + (size_t)(c + 3) * PADDED_N);
    }
    y[i] = (s0 + s1) + (s2 + s3);
}

// ---------------- Fallback (direct atomics) if ws too small ----------------
__global__ __launch_bounds__(256) void bias_init_kernel(
    const float* __restrict__ Param_b, const int* __restrict__ node_label,
    float* __restrict__ y, int n_nodes)
{
    int i = blockIdx.x * blockDim.x + threadIdx.x;
    if (i < n_nodes) y[i] = Param_b[node_label[i]];
}

__global__ __launch_bounds__(256) void edge_scatter_kernel(
    const float* __restrict__ x, const float* __restrict__ Param_W,
    const int* __restrict__ src, const int* __restrict__ dst,
    const int* __restrict__ widx, float* __restrict__ y, int n_edges)
{
    int i = (blockIdx.x * blockDim.x + threadIdx.x) * 4;
    if (i + 3 < n_edges) {
        int4 s = *reinterpret_cast<const int4*>(src + i);
        int4 d = *reinterpret_cast<const int4*>(dst + i);
        int4 w = *reinterpret_cast<const int4*>(widx + i);
        unsafeAtomicAdd(&y[d.x], Param_W[w.x] * x[s.x]);
        unsafeAtomicAdd(&y[d.y], Param_W[w.y] * x[s.y]);
        unsafeAtomicAdd(&y[d.z], Param_W[w.z] * x[s.z]);
        unsafeAtomicAdd(&y[d.w], Param_W[w.w] * x[s.w]);
    } else {
        for (; i < n_edges; ++i)
            unsafeAtomicAdd(&y[dst[i]], Param_W[widx[i]] * x[src[i]]);
    }
}

extern "C" void kernel_launch(void* const* d_in, const int* in_sizes, int n_in,
                              void* d_out, int out_size, void* d_ws, size_t ws_size,
                              hipStream_t stream)
{
    const float* x          = (const float*)d_in[0];
    const float* Param_W    = (const float*)d_in[1];
    const float* Param_b    = (const float*)d_in[2];
    const int*   src        = (const int*)d_in[3];
    const int*   dst        = (const int*)d_in[4];
    const int*   weight_idx = (const int*)d_in[5];
    const int*   node_label = (const int*)d_in[6];
    float* y = (float*)d_out;

    int n_nodes = in_sizes[0];
    int W_n     = in_sizes[1];
    int E       = in_sizes[3];

    size_t wh_bytes       = ((size_t)W_n * sizeof(__half) + 255) & ~(size_t)255;  // 2MB
    size_t partials_elems = (size_t)NCHUNKS * PADDED_N;                            // 39.3MB
    size_t need_bytes     = wh_bytes + partials_elems * sizeof(float);

    if (ws_size >= need_bytes) {
        __half* Wh       = (__half*)d_ws;
        float*  partials = (float*)((char*)d_ws + wh_bytes);

        // Phase 0: convert W to fp16 (ws re-poisoned every launch -> always rerun)
        int t0 = (W_n + 3) / 4;
        wconv_kernel<<<(t0 + 255) / 256, 256, 0, stream>>>(Param_W, Wh, W_n);

        // Fused pipelined gather+scan: 160 KB dynamic LDS, 240 blocks (1/CU)
        int chunk = (((E + NCHUNKS - 1) / NCHUNKS) + 3) & ~3;  // mult of 4
        fscan_kernel<<<PARTS * NCHUNKS, TPB_SCAN, NPP * sizeof(float), stream>>>(
            x, Wh, src, weight_idx, dst, partials, E, chunk);

        reduce5_kernel<<<(n_nodes + 255) / 256, 256, 0, stream>>>(
            partials, Param_b, node_label, y, n_nodes);
    } else {
        bias_init_kernel<<<(n_nodes + 255) / 256, 256, 0, stream>>>(
            Param_b, node_label, y, n_nodes);
        int t = (E + 3) / 4;
        edge_scatter_kernel<<<(t + 255) / 256, 256, 0, stream>>>(
            x, Param_W, src, dst, weight_idx, y, E);
    }
}